// Round 4
// baseline (450.911 us; speedup 1.0000x reference)
//
#include <hip/hip_runtime.h>

typedef float    f32x4 __attribute__((ext_vector_type(4)));
typedef __bf16   bf16x8 __attribute__((ext_vector_type(8)));
typedef _Float16 f16x4 __attribute__((ext_vector_type(4)));

static __device__ __forceinline__ unsigned short f2bf(float f) {
  union { float f; unsigned int u; } a; a.f = f;
  unsigned int r = (a.u + 0x7FFFu + ((a.u >> 16) & 1u)) >> 16;
  return (unsigned short)r;
}

// 1/sqrt(17) * log2(e): folded into Wq and posW_q so softmax uses exp2 directly
#define QSCALE_L2E 0.34992146f

// Weights -> bf16 MFMA fragments (A-frag for swapped Q/K proj, B-frag for
// normal V proj; identical lane mapping).
// wf[((w*32 + n*4 + kk)*512) + p*8 + i] = W_w[kk*32+(p>>4)*8+i][n*16+(p&15)]
__global__ void prep_weights(const float* __restrict__ Wq, const float* __restrict__ Wk,
                             const float* __restrict__ Wv, unsigned short* __restrict__ wf) {
  int idx = blockIdx.x * 256 + threadIdx.x;
  if (idx >= 3 * 8 * 4 * 64 * 8) return;
  int i  = idx & 7;
  int p  = (idx >> 3) & 63;
  int kk = (idx >> 9) & 3;
  int n  = (idx >> 11) & 7;
  int w  = idx >> 14;
  const float* W = (w == 0) ? Wq : ((w == 1) ? Wk : Wv);
  float val = W[(kk * 32 + (p >> 4) * 8 + i) * 128 + n * 16 + (p & 15)];
  if (w == 0) val *= QSCALE_L2E;
  wf[idx] = f2bf(val);
}

// posW[w][t][d] accumulator-init fragments, per lane:
//  w<2 (swapped):  acc[r] = posW[t=l&15][d=h*16+(l>>4)*4+r]
//  w==2 (normal):  acc[r] = posW[t=(l>>4)*4+r][d=h*16+(l&15)]
__global__ void prep_posw(const float* __restrict__ pos, const float* __restrict__ Wq,
                          const float* __restrict__ Wk, const float* __restrict__ Wv,
                          float* __restrict__ pw) {
  int idx = blockIdx.x * 256 + threadIdx.x;
  if (idx >= 3 * 8 * 64 * 4) return;
  int r = idx & 3;
  int l = (idx >> 2) & 63;
  int h = (idx >> 8) & 7;
  int w = idx >> 11;
  const float* W = (w == 0) ? Wq : ((w == 1) ? Wk : Wv);
  int t, d;
  if (w < 2) { t = l & 15;            d = h * 16 + (l >> 4) * 4 + r; }
  else       { t = (l >> 4) * 4 + r;  d = h * 16 + (l & 15); }
  float s = 0.f;
  for (int k = 0; k < 128; ++k) s += pos[t * 128 + k] * W[k * 128 + d];
  if (w == 0) s *= QSCALE_L2E;
  pw[idx] = s;
}

__attribute__((amdgpu_waves_per_eu(3)))
__global__ void __launch_bounds__(256)
attn_main(const float* __restrict__ xin, const float* __restrict__ pos,
          const unsigned short* __restrict__ wfrag, const float* __restrict__ pw,
          float* __restrict__ out, int B) {
  const int tid  = threadIdx.x;
  const int wid  = tid >> 6;            // wave 0..3
  const int l    = tid & 63;
  const int frow = l & 15;
  const int fkq  = l >> 4;
  const int trow0 = fkq * 4;
  const int hblk = blockIdx.x & 1;      // head group: 0 -> heads 0..3, 1 -> 4..7
  const int head = hblk * 4 + wid;

  // resident per-lane state: 12 + 4 regs only
  f32x4 posw[3];
#pragma unroll
  for (int w = 0; w < 3; ++w)
    posw[w] = *(const f32x4*)(pw + ((w * 8 + head) * 64 + l) * 4);
  const int ptoff = hblk * 64 + wid * 16 + fkq * 4;   // pass-through col slice
  const f32x4 posp = *(const f32x4*)(pos + frow * 128 + ptoff);

  const unsigned short* wbase = wfrag + head * 4 * 512 + l * 8;
  const f32x4 zero4 = {0.f, 0.f, 0.f, 0.f};

  for (int b0 = (blockIdx.x >> 1) * 2; b0 < B; b0 += gridDim.x) {
    // ---- stream this head's 12 weight fragments from L2 (laundered pointer
    //      prevents LICM from making them register/AGPR-resident) ----
    const unsigned short* wp = wbase;
    asm volatile("" : "+v"(wp));
    bf16x8 wv_[3][4];
#pragma unroll
    for (int w = 0; w < 3; ++w)
#pragma unroll
      for (int kk = 0; kk < 4; ++kk)
        wv_[w][kk] = *(const bf16x8*)(wp + (w * 32 + kk) * 512);

    // ---- two independent batch chains share the streamed weights ----
#pragma unroll
    for (int g = 0; g < 2; ++g) {
      const float* xb = xin + (size_t)(b0 + g) * 2048;
      float* ob = out + (size_t)(b0 + g) * 4096;

      bf16x8 xf[4];
#pragma unroll
      for (int kk = 0; kk < 4; ++kk) {
        const float* xp = xb + frow * 128 + kk * 32 + fkq * 8;
        f32x4 a0 = *(const f32x4*)xp;
        f32x4 a1 = *(const f32x4*)(xp + 4);
        xf[kk][0] = (__bf16)a0.x; xf[kk][1] = (__bf16)a0.y;
        xf[kk][2] = (__bf16)a0.z; xf[kk][3] = (__bf16)a0.w;
        xf[kk][4] = (__bf16)a1.x; xf[kk][5] = (__bf16)a1.y;
        xf[kk][6] = (__bf16)a1.z; xf[kk][7] = (__bf16)a1.w;
      }
      // pass-through slice: out[:, :, 128:256] = x + pos (fp32 exact)
      f32x4 ptv = *(const f32x4*)(xb + frow * 128 + ptoff) + posp;
      *(f32x4*)(ob + frow * 256 + 128 + ptoff) = ptv;

      // projections: Q,K swapped (W as A -> Q^T/K^T), V normal
      f32x4 qa = posw[0], ka = posw[1], va = posw[2];
#pragma unroll
      for (int kk = 0; kk < 4; ++kk) {
        qa = __builtin_amdgcn_mfma_f32_16x16x32_bf16(wv_[0][kk], xf[kk], qa, 0, 0, 0);
        ka = __builtin_amdgcn_mfma_f32_16x16x32_bf16(wv_[1][kk], xf[kk], ka, 0, 0, 0);
        va = __builtin_amdgcn_mfma_f32_16x16x32_bf16(xf[kk], wv_[2][kk], va, 0, 0, 0);
      }
      f16x4 qh, kh, vh;
#pragma unroll
      for (int r = 0; r < 4; ++r) {
        qh[r] = (_Float16)qa[r];
        kh[r] = (_Float16)ka[r];
        vh[r] = (_Float16)va[r];
      }

      // scores^T = K · Q^T; log2e pre-folded -> exp2 directly; no max-sub
      f32x4 st = __builtin_amdgcn_mfma_f32_16x16x16f16(kh, qh, zero4, 0, 0, 0);
      float p0 = (trow0 + 0 <= frow) ? exp2f(st[0]) : 0.f;
      float p1 = (trow0 + 1 <= frow) ? exp2f(st[1]) : 0.f;
      float p2 = (trow0 + 2 <= frow) ? exp2f(st[2]) : 0.f;
      float p3 = (trow0 + 3 <= frow) ? exp2f(st[3]) : 0.f;
      float ssum = (p0 + p1) + (p2 + p3);
      ssum += __shfl_xor(ssum, 16);
      ssum += __shfl_xor(ssum, 32);
      float inv = __builtin_amdgcn_rcpf(ssum);
      f16x4 ah;
      ah[0] = (_Float16)(p0 * inv);
      ah[1] = (_Float16)(p1 * inv);
      ah[2] = (_Float16)(p2 * inv);
      ah[3] = (_Float16)(p3 * inv);

      // o^T = V^T · attn^T ; relu(o)+o ; store
      f32x4 ot = __builtin_amdgcn_mfma_f32_16x16x16f16(vh, ah, zero4, 0, 0, 0);
      f32x4 ov;
#pragma unroll
      for (int r = 0; r < 4; ++r) {
        float x = ot[r];
        ov[r] = x > 0.f ? 2.f * x : x;
      }
      *(f32x4*)(ob + frow * 256 + head * 16 + trow0) = ov;
    }
  }
}

extern "C" void kernel_launch(void* const* d_in, const int* in_sizes, int n_in,
                              void* d_out, int out_size, void* d_ws, size_t ws_size,
                              hipStream_t stream) {
  (void)n_in; (void)out_size; (void)ws_size;
  const float* xin = (const float*)d_in[0];
  const float* pos = (const float*)d_in[1];
  const float* Wq  = (const float*)d_in[2];
  const float* Wk  = (const float*)d_in[3];
  const float* Wv  = (const float*)d_in[4];
  float* out = (float*)d_out;
  unsigned short* wf = (unsigned short*)d_ws;            // 96 KiB
  float* pw = (float*)((char*)d_ws + 3 * 8 * 4 * 64 * 8 * sizeof(unsigned short));  // 24 KiB
  int B = in_sizes[0] / 2048;

  hipLaunchKernelGGL(prep_weights, dim3(192), dim3(256), 0, stream, Wq, Wk, Wv, wf);
  hipLaunchKernelGGL(prep_posw, dim3(24), dim3(256), 0, stream, pos, Wq, Wk, Wv, pw);
  hipLaunchKernelGGL(attn_main, dim3(4096), dim3(256), 0, stream, xin, pos, wf, pw, out, B);
}

// Round 5
// 234.602 us; speedup vs baseline: 1.9220x; 1.9220x over previous
//
#include <hip/hip_runtime.h>

typedef float    f32x4 __attribute__((ext_vector_type(4)));
typedef __bf16   bf16x8 __attribute__((ext_vector_type(8)));
typedef _Float16 f16x4 __attribute__((ext_vector_type(4)));

static __device__ __forceinline__ unsigned short f2bf(float f) {
  union { float f; unsigned int u; } a; a.f = f;
  unsigned int r = (a.u + 0x7FFFu + ((a.u >> 16) & 1u)) >> 16;
  return (unsigned short)r;
}

// 1/sqrt(17) * log2(e): folded into Wq and posW_q so softmax uses exp2 directly
#define QSCALE_L2E 0.34992146f

// Weights -> bf16 MFMA fragments (A-frag for swapped Q/K proj, B-frag for
// normal V proj; identical lane mapping).
// wf[((w*32 + n*4 + kk)*512) + p*8 + i] = W_w[kk*32+(p>>4)*8+i][n*16+(p&15)]
__global__ void prep_weights(const float* __restrict__ Wq, const float* __restrict__ Wk,
                             const float* __restrict__ Wv, unsigned short* __restrict__ wf) {
  int idx = blockIdx.x * 256 + threadIdx.x;
  if (idx >= 3 * 8 * 4 * 64 * 8) return;
  int i  = idx & 7;
  int p  = (idx >> 3) & 63;
  int kk = (idx >> 9) & 3;
  int n  = (idx >> 11) & 7;
  int w  = idx >> 14;
  const float* W = (w == 0) ? Wq : ((w == 1) ? Wk : Wv);
  float val = W[(kk * 32 + (p >> 4) * 8 + i) * 128 + n * 16 + (p & 15)];
  if (w == 0) val *= QSCALE_L2E;
  wf[idx] = f2bf(val);
}

// posW[w][t][d] accumulator-init fragments, per lane:
//  w<2 (swapped):  acc[r] = posW[t=l&15][d=h*16+(l>>4)*4+r]
//  w==2 (normal):  acc[r] = posW[t=(l>>4)*4+r][d=h*16+(l&15)]
__global__ void prep_posw(const float* __restrict__ pos, const float* __restrict__ Wq,
                          const float* __restrict__ Wk, const float* __restrict__ Wv,
                          float* __restrict__ pw) {
  int idx = blockIdx.x * 256 + threadIdx.x;
  if (idx >= 3 * 8 * 64 * 4) return;
  int r = idx & 3;
  int l = (idx >> 2) & 63;
  int h = (idx >> 8) & 7;
  int w = idx >> 11;
  const float* W = (w == 0) ? Wq : ((w == 1) ? Wk : Wv);
  int t, d;
  if (w < 2) { t = l & 15;            d = h * 16 + (l >> 4) * 4 + r; }
  else       { t = (l >> 4) * 4 + r;  d = h * 16 + (l & 15); }
  float s = 0.f;
  for (int k = 0; k < 128; ++k) s += pos[t * 128 + k] * W[k * 128 + d];
  if (w == 0) s *= QSCALE_L2E;
  pw[idx] = s;
}

// Round-1 launch configuration (the empirically best one) + round-2 zero-LDS
// swapped-operand attention math. 4 waves/block, wave owns heads {2w, 2w+1};
// weights preloaded ONCE outside the batch loop, no residency attributes.
__global__ void __launch_bounds__(256, 2)
attn_main(const float* __restrict__ xin, const float* __restrict__ pos,
          const unsigned short* __restrict__ wfrag, const float* __restrict__ pw,
          float* __restrict__ out, int B) {
  const int tid   = threadIdx.x;
  const int wid   = tid >> 6;   // wave 0..3
  const int l     = tid & 63;
  const int frow  = l & 15;
  const int fkq   = l >> 4;
  const int trow0 = fkq * 4;
  const int n0    = wid * 2;    // first head owned by this wave

  // weight fragments for this wave's 2 heads: 24 frags = 96 VGPRs
  bf16x8 wf[3][2][4];
#pragma unroll
  for (int w = 0; w < 3; ++w)
#pragma unroll
    for (int hl = 0; hl < 2; ++hl)
#pragma unroll
      for (int kk = 0; kk < 4; ++kk)
        wf[w][hl][kk] = *(const bf16x8*)(wfrag + ((w * 32 + (n0 + hl) * 4 + kk) * 512) + l * 8);

  // pos*W accumulator-init fragments: 24 VGPRs
  f32x4 posw[3][2];
#pragma unroll
  for (int w = 0; w < 3; ++w)
#pragma unroll
    for (int hl = 0; hl < 2; ++hl)
      posw[w][hl] = *(const f32x4*)(pw + ((w * 8 + n0 + hl) * 64 + l) * 4);

  // pass-through pos slice: wave wid covers feature cols wid*32..wid*32+31
  const int ptc = wid * 32 + fkq * 8;
  const f32x4 pp0 = *(const f32x4*)(pos + frow * 128 + ptc);
  const f32x4 pp1 = *(const f32x4*)(pos + frow * 128 + ptc + 4);

  const f32x4 zero4 = {0.f, 0.f, 0.f, 0.f};

  for (int b = blockIdx.x; b < B; b += gridDim.x) {
    const float* xb = xin + (size_t)b * 2048;
    float* ob = out + (size_t)b * 4096;

    // ---- x row fragments (B-frag layout); pass-through slice reused from them ----
    bf16x8 xf[4];
    f32x4 pt0, pt1;
#pragma unroll
    for (int kk = 0; kk < 4; ++kk) {
      const float* xp = xb + frow * 128 + kk * 32 + fkq * 8;
      f32x4 a0 = *(const f32x4*)xp;
      f32x4 a1 = *(const f32x4*)(xp + 4);
      if (kk == wid) { pt0 = a0 + pp0; pt1 = a1 + pp1; }  // wave-uniform select
      xf[kk][0] = (__bf16)a0.x; xf[kk][1] = (__bf16)a0.y;
      xf[kk][2] = (__bf16)a0.z; xf[kk][3] = (__bf16)a0.w;
      xf[kk][4] = (__bf16)a1.x; xf[kk][5] = (__bf16)a1.y;
      xf[kk][6] = (__bf16)a1.z; xf[kk][7] = (__bf16)a1.w;
    }
    // pass-through store: out[:, :, 128:256] = x + pos (fp32 exact)
    *(f32x4*)(ob + frow * 256 + 128 + ptc) = pt0;
    *(f32x4*)(ob + frow * 256 + 128 + ptc + 4) = pt1;

    // ---- per head: proj (Q,K swapped; V normal) -> attention fully in-register ----
#pragma unroll
    for (int hl = 0; hl < 2; ++hl) {
      f32x4 qa = posw[0][hl], ka = posw[1][hl], va = posw[2][hl];
#pragma unroll
      for (int kk = 0; kk < 4; ++kk) {
        qa = __builtin_amdgcn_mfma_f32_16x16x32_bf16(wf[0][hl][kk], xf[kk], qa, 0, 0, 0);
        ka = __builtin_amdgcn_mfma_f32_16x16x32_bf16(wf[1][hl][kk], xf[kk], ka, 0, 0, 0);
        va = __builtin_amdgcn_mfma_f32_16x16x32_bf16(xf[kk], wf[2][hl][kk], va, 0, 0, 0);
      }
      f16x4 qh, kh, vh;
#pragma unroll
      for (int r = 0; r < 4; ++r) {
        qh[r] = (_Float16)qa[r];
        kh[r] = (_Float16)ka[r];
        vh[r] = (_Float16)va[r];
      }

      // scores^T = K · Q^T (lane holds S^T[s=trow0+r][t=frow]); log2e prefolded
      f32x4 st = __builtin_amdgcn_mfma_f32_16x16x16f16(kh, qh, zero4, 0, 0, 0);
      float p0 = (trow0 + 0 <= frow) ? exp2f(st[0]) : 0.f;
      float p1 = (trow0 + 1 <= frow) ? exp2f(st[1]) : 0.f;
      float p2 = (trow0 + 2 <= frow) ? exp2f(st[2]) : 0.f;
      float p3 = (trow0 + 3 <= frow) ? exp2f(st[3]) : 0.f;
      float ssum = (p0 + p1) + (p2 + p3);
      ssum += __shfl_xor(ssum, 16);
      ssum += __shfl_xor(ssum, 32);
      float inv = __builtin_amdgcn_rcpf(ssum);
      f16x4 ah;
      ah[0] = (_Float16)(p0 * inv);
      ah[1] = (_Float16)(p1 * inv);
      ah[2] = (_Float16)(p2 * inv);
      ah[3] = (_Float16)(p3 * inv);

      // o^T = V^T · attn^T (lane holds o[t=frow][d=trow0+r]); relu(o)+o; store
      f32x4 ot = __builtin_amdgcn_mfma_f32_16x16x16f16(vh, ah, zero4, 0, 0, 0);
      f32x4 ov;
#pragma unroll
      for (int r = 0; r < 4; ++r) {
        float x = ot[r];
        ov[r] = x > 0.f ? 2.f * x : x;
      }
      *(f32x4*)(ob + frow * 256 + (n0 + hl) * 16 + trow0) = ov;
    }
  }
}

extern "C" void kernel_launch(void* const* d_in, const int* in_sizes, int n_in,
                              void* d_out, int out_size, void* d_ws, size_t ws_size,
                              hipStream_t stream) {
  (void)n_in; (void)out_size; (void)ws_size;
  const float* xin = (const float*)d_in[0];
  const float* pos = (const float*)d_in[1];
  const float* Wq  = (const float*)d_in[2];
  const float* Wk  = (const float*)d_in[3];
  const float* Wv  = (const float*)d_in[4];
  float* out = (float*)d_out;
  unsigned short* wf = (unsigned short*)d_ws;            // 96 KiB
  float* pw = (float*)((char*)d_ws + 3 * 8 * 4 * 64 * 8 * sizeof(unsigned short));  // 24 KiB
  int B = in_sizes[0] / 2048;

  hipLaunchKernelGGL(prep_weights, dim3(192), dim3(256), 0, stream, Wq, Wk, Wv, wf);
  hipLaunchKernelGGL(prep_posw, dim3(24), dim3(256), 0, stream, pos, Wq, Wk, Wv, pw);
  hipLaunchKernelGGL(attn_main, dim3(2048), dim3(256), 0, stream, xin, pos, wf, pw, out, B);
}